// Round 5
// baseline (282.905 us; speedup 1.0000x reference)
//
#include <hip/hip_runtime.h>
#include <math.h>

#define NCLS  1000
#define NROWS 16384
#define INV_TEMP 0.5f
#define NEG_INF (-INFINITY)

// ext_vector float4 so __builtin_nontemporal_load applies cleanly
typedef float vf4 __attribute__((ext_vector_type(4)));

__device__ __forceinline__ vf4 ldnt(const vf4* p) {
    return __builtin_nontemporal_load(p);
}

// merge two ordered top-2 pairs: (a1>=a2) U (b1>=b2) -> (a1,a2)
__device__ __forceinline__ void merge2(float& a1, float& a2, float b1, float b2) {
    const float mn = fminf(a1, b1);
    a1 = fmaxf(a1, b1);
    a2 = fmaxf(mn, fmaxf(a2, b2));
}

// thread-local top-2 of 4 vf4 (16 values)
__device__ __forceinline__ void top2_16(const vf4 v0, const vf4 v1,
                                        const vf4 v2, const vf4 v3,
                                        float& m1, float& m2)
{
    float t1[4], t2[4];
    const vf4 vv[4] = {v0, v1, v2, v3};
    #pragma unroll
    for (int i = 0; i < 4; ++i) {
        const float hi1 = fmaxf(vv[i].x, vv[i].y), lo1 = fminf(vv[i].x, vv[i].y);
        const float hi2 = fmaxf(vv[i].z, vv[i].w), lo2 = fminf(vv[i].z, vv[i].w);
        t1[i] = fmaxf(hi1, hi2);
        t2[i] = fmaxf(fminf(hi1, hi2), fmaxf(lo1, lo2));
    }
    merge2(t1[0], t2[0], t1[1], t2[1]);
    merge2(t1[2], t2[2], t1[3], t2[3]);
    merge2(t1[0], t2[0], t1[2], t2[2]);
    m1 = t1[0]; m2 = t2[0];
}

// pick component of the target's float4 (owner lane holds it; others garbage-ok)
__device__ __forceinline__ float pick(const vf4 v0, const vf4 v1,
                                      const vf4 v2, const vf4 v3,
                                      int chunk, int comp)
{
    const vf4 sel = (chunk == 0) ? v0 : (chunk == 1) ? v1
                  : (chunk == 2) ? v2 : v3;
    return (comp == 0) ? sel.x : (comp == 1) ? sel.y
         : (comp == 2) ? sel.z : sel.w;
}

// Region-coherent cache split:
//   o1, o2  (128 MB): non-temporal -> contiguous HBM miss streams, no L3
//                     allocation (HBM page locality preserved)
//   o3,o4,mim (192 MB < 256 MB L3): cached loads -> stabilize L3-resident
//                     (nt streams cannot evict them), served at L3 BW
// nt (HBM-latency) loads issued first; cached loads after; everything else
// identical to the round-4 kernel.
__global__ __launch_bounds__(256) void fused_margin_softmax(
    const float* __restrict__ o1, const float* __restrict__ o2,
    const float* __restrict__ o3, const float* __restrict__ o4,
    const float* __restrict__ mim, const int* __restrict__ targets,
    float* __restrict__ out, float* __restrict__ wavemax)
{
    const int lane = threadIdx.x & 63;
    const int row  = blockIdx.x * 4 + (threadIdx.x >> 6);   // wave-uniform

    const int tgt = targets[row];            // first load issued; cached
    const int q     = tgt >> 2;
    const int comp  = tgt & 3;
    const int chunk = q >> 6;
    const int src   = q & 63;                // owning lane (always < 58 in chunk 3)

    const int i3 = (lane < 58) ? (192 + lane) : 249;
    const vf4* pa = (const vf4*)(o1  + (size_t)row * NCLS);
    const vf4* pb = (const vf4*)(o2  + (size_t)row * NCLS);
    const vf4* pc = (const vf4*)(o3  + (size_t)row * NCLS);
    const vf4* pd = (const vf4*)(o4  + (size_t)row * NCLS);
    const vf4* pe = (const vf4*)(mim + (size_t)row * NCLS);

    // HBM-bound nt streams first (longest latency, in flight the longest)
    vf4 a0 = ldnt(pa + lane), a1 = ldnt(pa + 64 + lane),
        a2 = ldnt(pa + 128 + lane), a3 = ldnt(pa + i3);
    vf4 b0 = ldnt(pb + lane), b1 = ldnt(pb + 64 + lane),
        b2 = ldnt(pb + 128 + lane), b3 = ldnt(pb + i3);
    // L3-resident cached streams
    vf4 c0 = pc[lane], c1 = pc[64 + lane], c2 = pc[128 + lane], c3 = pc[i3];
    vf4 d0 = pd[lane], d1 = pd[64 + lane], d2 = pd[128 + lane], d3 = pd[i3];
    vf4 e0 = pe[lane], e1 = pe[64 + lane], e2 = pe[128 + lane], e3 = pe[i3];

    // target-value candidates (pre-tail-mask: owner lane is never masked)
    float tvc[5];
    tvc[0] = pick(a0, a1, a2, a3, chunk, comp);
    tvc[1] = pick(b0, b1, b2, b3, chunk, comp);
    tvc[2] = pick(c0, c1, c2, c3, chunk, comp);
    tvc[3] = pick(d0, d1, d2, d3, chunk, comp);
    tvc[4] = pick(e0, e1, e2, e3, chunk, comp);

    if (lane >= 58) {
        const vf4 n4 = {NEG_INF, NEG_INF, NEG_INF, NEG_INF};
        a3 = n4; b3 = n4; c3 = n4; d3 = n4; e3 = n4;
    }

    // thread-local top2 per matrix
    float t1[5], t2[5];
    top2_16(a0, a1, a2, a3, t1[0], t2[0]);
    top2_16(b0, b1, b2, b3, t1[1], t2[1]);
    top2_16(c0, c1, c2, c3, t1[2], t2[2]);
    top2_16(d0, d1, d2, d3, t1[3], t2[3]);
    top2_16(e0, e1, e2, e3, t1[4], t2[4]);

    // broadcast the 5 target values
    float tv[5];
    #pragma unroll
    for (int m = 0; m < 5; ++m) tv[m] = __shfl(tvc[m], src, 64);

    // single interleaved butterfly: 6 steps x 10 independent shuffles
    #pragma unroll
    for (int off = 32; off >= 1; off >>= 1) {
        float q1[5], q2[5];
        #pragma unroll
        for (int m = 0; m < 5; ++m) {
            q1[m] = __shfl_xor(t1[m], off, 64);
            q2[m] = __shfl_xor(t2[m], off, 64);
        }
        #pragma unroll
        for (int m = 0; m < 5; ++m) merge2(t1[m], t2[m], q1[m], q2[m]);
    }

    // margins + row max (mats 0..3)
    float g[5];
    #pragma unroll
    for (int m = 0; m < 5; ++m)
        g[m] = (t1[m] == tv[m]) ? (t1[m] - t2[m]) : 0.0f;
    const float rowmax = fmaxf(fmaxf(t1[0], t1[1]), fmaxf(t1[2], t1[3]));

    // fused softmax (wave-uniform)
    const float p0 = g[0] * INV_TEMP, p1 = g[1] * INV_TEMP, p2 = g[2] * INV_TEMP,
                p3 = g[3] * INV_TEMP, p4 = g[4] * INV_TEMP;
    const float pm = fmaxf(fmaxf(fmaxf(p0, p1), fmaxf(p2, p3)), p4);
    const float x0 = expf(p0 - pm), x1 = expf(p1 - pm), x2 = expf(p2 - pm),
                x3 = expf(p3 - pm), x4 = expf(p4 - pm);
    const float inv = 1.0f / (x0 + x1 + x2 + x3 + x4);

    if (lane < 5) {
        const float r = (lane == 0) ? x0 : (lane == 1) ? x1 : (lane == 2) ? x2
                      : (lane == 3) ? x3 : x4;
        out[1 + (size_t)row * 5 + lane] = r * inv;
    }
    if (lane == 5) wavemax[row] = rowmax;
}

// Single block of 1024 threads reduces wavemax[16384] -> out[0].
__global__ __launch_bounds__(1024) void final_max_kernel(
    const float* __restrict__ wavemax, float* __restrict__ out)
{
    const float4* w4 = (const float4*)wavemax;
    float m = NEG_INF;
    #pragma unroll
    for (int i = 0; i < (NROWS / 4) / 1024; ++i) {
        const float4 v = w4[threadIdx.x + i * 1024];
        m = fmaxf(fmaxf(fmaxf(m, v.x), v.y), fmaxf(v.z, v.w));
    }
    #pragma unroll
    for (int off = 32; off >= 1; off >>= 1)
        m = fmaxf(m, __shfl_xor(m, off, 64));
    __shared__ float s[16];
    const int lane = threadIdx.x & 63, wid = threadIdx.x >> 6;
    if (lane == 0) s[wid] = m;
    __syncthreads();
    if (threadIdx.x == 0) {
        float mm = s[0];
        #pragma unroll
        for (int i = 1; i < 16; ++i) mm = fmaxf(mm, s[i]);
        out[0] = mm;
    }
}

extern "C" void kernel_launch(void* const* d_in, const int* in_sizes, int n_in,
                              void* d_out, int out_size, void* d_ws, size_t ws_size,
                              hipStream_t stream) {
    const float* o1  = (const float*)d_in[0];
    const float* o2  = (const float*)d_in[1];
    const float* o3  = (const float*)d_in[2];
    const float* o4  = (const float*)d_in[3];
    const float* mim = (const float*)d_in[4];
    const int*   tgt = (const int*)d_in[5];

    float* out = (float*)d_out;
    float* wavemax = (float*)d_ws;                   // NROWS floats (64 KB)

    fused_margin_softmax<<<NROWS / 4, 256, 0, stream>>>(o1, o2, o3, o4, mim, tgt,
                                                        out, wavemax);
    final_max_kernel<<<1, 1024, 0, stream>>>(wavemax, out);
}

// Round 6
// 264.686 us; speedup vs baseline: 1.0688x; 1.0688x over previous
//
#include <hip/hip_runtime.h>
#include <math.h>

#define NCLS  1000
#define NROWS 16384
#define INV_TEMP 0.5f
#define NEG_INF (-INFINITY)

// ext_vector float4 so __builtin_nontemporal_load applies cleanly
typedef float vf4 __attribute__((ext_vector_type(4)));

__device__ __forceinline__ vf4 ldnt(const vf4* p) {
    return __builtin_nontemporal_load(p);
}

// merge two ordered top-2 pairs: (a1>=a2) U (b1>=b2) -> (a1,a2)
__device__ __forceinline__ void merge2(float& a1, float& a2, float b1, float b2) {
    const float mn = fminf(a1, b1);
    a1 = fmaxf(a1, b1);
    a2 = fmaxf(mn, fmaxf(a2, b2));
}

// thread-local top-2 of 4 vf4 (16 values)
__device__ __forceinline__ void top2_16(const vf4 v0, const vf4 v1,
                                        const vf4 v2, const vf4 v3,
                                        float& m1, float& m2)
{
    float t1[4], t2[4];
    const vf4 vv[4] = {v0, v1, v2, v3};
    #pragma unroll
    for (int i = 0; i < 4; ++i) {
        const float hi1 = fmaxf(vv[i].x, vv[i].y), lo1 = fminf(vv[i].x, vv[i].y);
        const float hi2 = fmaxf(vv[i].z, vv[i].w), lo2 = fminf(vv[i].z, vv[i].w);
        t1[i] = fmaxf(hi1, hi2);
        t2[i] = fmaxf(fminf(hi1, hi2), fmaxf(lo1, lo2));
    }
    merge2(t1[0], t2[0], t1[1], t2[1]);
    merge2(t1[2], t2[2], t1[3], t2[3]);
    merge2(t1[0], t2[0], t1[2], t2[2]);
    m1 = t1[0]; m2 = t2[0];
}

// pick component of the target's float4 (owner lane holds it; others garbage-ok)
__device__ __forceinline__ float pick(const vf4 v0, const vf4 v1,
                                      const vf4 v2, const vf4 v3,
                                      int chunk, int comp)
{
    const vf4 sel = (chunk == 0) ? v0 : (chunk == 1) ? v1
                  : (chunk == 2) ? v2 : v3;
    return (comp == 0) ? sel.x : (comp == 1) ? sel.y
         : (comp == 2) ? sel.z : sel.w;
}

// ALL 20 row loads non-temporal (round-4 winner, 55 us / 5.96 TB/s ingest):
// nt bypasses L2 allocation, lifting the cached-load ~2.9 TB/s throttle.
// Outputs stored non-temporal too (no reuse, don't allocate lines).
__global__ __launch_bounds__(256) void fused_margin_softmax(
    const float* __restrict__ o1, const float* __restrict__ o2,
    const float* __restrict__ o3, const float* __restrict__ o4,
    const float* __restrict__ mim, const int* __restrict__ targets,
    float* __restrict__ out, float* __restrict__ wavemax)
{
    const int lane = threadIdx.x & 63;
    const int row  = blockIdx.x * 4 + (threadIdx.x >> 6);   // wave-uniform

    const int tgt = targets[row];            // first load issued; cached (tiny)
    const int q     = tgt >> 2;
    const int comp  = tgt & 3;
    const int chunk = q >> 6;
    const int src   = q & 63;                // owning lane (always < 58 in chunk 3)

    const int i3 = (lane < 58) ? (192 + lane) : 249;
    const vf4* pa = (const vf4*)(o1  + (size_t)row * NCLS);
    const vf4* pb = (const vf4*)(o2  + (size_t)row * NCLS);
    const vf4* pc = (const vf4*)(o3  + (size_t)row * NCLS);
    const vf4* pd = (const vf4*)(o4  + (size_t)row * NCLS);
    const vf4* pe = (const vf4*)(mim + (size_t)row * NCLS);

    vf4 a0 = ldnt(pa + lane), a1 = ldnt(pa + 64 + lane),
        a2 = ldnt(pa + 128 + lane), a3 = ldnt(pa + i3);
    vf4 b0 = ldnt(pb + lane), b1 = ldnt(pb + 64 + lane),
        b2 = ldnt(pb + 128 + lane), b3 = ldnt(pb + i3);
    vf4 c0 = ldnt(pc + lane), c1 = ldnt(pc + 64 + lane),
        c2 = ldnt(pc + 128 + lane), c3 = ldnt(pc + i3);
    vf4 d0 = ldnt(pd + lane), d1 = ldnt(pd + 64 + lane),
        d2 = ldnt(pd + 128 + lane), d3 = ldnt(pd + i3);
    vf4 e0 = ldnt(pe + lane), e1 = ldnt(pe + 64 + lane),
        e2 = ldnt(pe + 128 + lane), e3 = ldnt(pe + i3);

    // target-value candidates (pre-tail-mask: owner lane is never masked)
    float tvc[5];
    tvc[0] = pick(a0, a1, a2, a3, chunk, comp);
    tvc[1] = pick(b0, b1, b2, b3, chunk, comp);
    tvc[2] = pick(c0, c1, c2, c3, chunk, comp);
    tvc[3] = pick(d0, d1, d2, d3, chunk, comp);
    tvc[4] = pick(e0, e1, e2, e3, chunk, comp);

    if (lane >= 58) {
        const vf4 n4 = {NEG_INF, NEG_INF, NEG_INF, NEG_INF};
        a3 = n4; b3 = n4; c3 = n4; d3 = n4; e3 = n4;
    }

    // thread-local top2 per matrix
    float t1[5], t2[5];
    top2_16(a0, a1, a2, a3, t1[0], t2[0]);
    top2_16(b0, b1, b2, b3, t1[1], t2[1]);
    top2_16(c0, c1, c2, c3, t1[2], t2[2]);
    top2_16(d0, d1, d2, d3, t1[3], t2[3]);
    top2_16(e0, e1, e2, e3, t1[4], t2[4]);

    // broadcast the 5 target values
    float tv[5];
    #pragma unroll
    for (int m = 0; m < 5; ++m) tv[m] = __shfl(tvc[m], src, 64);

    // single interleaved butterfly: 6 steps x 10 independent shuffles
    #pragma unroll
    for (int off = 32; off >= 1; off >>= 1) {
        float q1[5], q2[5];
        #pragma unroll
        for (int m = 0; m < 5; ++m) {
            q1[m] = __shfl_xor(t1[m], off, 64);
            q2[m] = __shfl_xor(t2[m], off, 64);
        }
        #pragma unroll
        for (int m = 0; m < 5; ++m) merge2(t1[m], t2[m], q1[m], q2[m]);
    }

    // margins + row max (mats 0..3)
    float g[5];
    #pragma unroll
    for (int m = 0; m < 5; ++m)
        g[m] = (t1[m] == tv[m]) ? (t1[m] - t2[m]) : 0.0f;
    const float rowmax = fmaxf(fmaxf(t1[0], t1[1]), fmaxf(t1[2], t1[3]));

    // fused softmax (wave-uniform)
    const float p0 = g[0] * INV_TEMP, p1 = g[1] * INV_TEMP, p2 = g[2] * INV_TEMP,
                p3 = g[3] * INV_TEMP, p4 = g[4] * INV_TEMP;
    const float pm = fmaxf(fmaxf(fmaxf(p0, p1), fmaxf(p2, p3)), p4);
    const float x0 = expf(p0 - pm), x1 = expf(p1 - pm), x2 = expf(p2 - pm),
                x3 = expf(p3 - pm), x4 = expf(p4 - pm);
    const float inv = 1.0f / (x0 + x1 + x2 + x3 + x4);

    if (lane < 5) {
        const float r = (lane == 0) ? x0 : (lane == 1) ? x1 : (lane == 2) ? x2
                      : (lane == 3) ? x3 : x4;
        __builtin_nontemporal_store(r * inv, out + 1 + (size_t)row * 5 + lane);
    }
    if (lane == 5) __builtin_nontemporal_store(rowmax, wavemax + row);
}

// Single block of 1024 threads reduces wavemax[16384] -> out[0].
__global__ __launch_bounds__(1024) void final_max_kernel(
    const float* __restrict__ wavemax, float* __restrict__ out)
{
    const float4* w4 = (const float4*)wavemax;
    float m = NEG_INF;
    #pragma unroll
    for (int i = 0; i < (NROWS / 4) / 1024; ++i) {
        const float4 v = w4[threadIdx.x + i * 1024];
        m = fmaxf(fmaxf(fmaxf(m, v.x), v.y), fmaxf(v.z, v.w));
    }
    #pragma unroll
    for (int off = 32; off >= 1; off >>= 1)
        m = fmaxf(m, __shfl_xor(m, off, 64));
    __shared__ float s[16];
    const int lane = threadIdx.x & 63, wid = threadIdx.x >> 6;
    if (lane == 0) s[wid] = m;
    __syncthreads();
    if (threadIdx.x == 0) {
        float mm = s[0];
        #pragma unroll
        for (int i = 1; i < 16; ++i) mm = fmaxf(mm, s[i]);
        out[0] = mm;
    }
}

extern "C" void kernel_launch(void* const* d_in, const int* in_sizes, int n_in,
                              void* d_out, int out_size, void* d_ws, size_t ws_size,
                              hipStream_t stream) {
    const float* o1  = (const float*)d_in[0];
    const float* o2  = (const float*)d_in[1];
    const float* o3  = (const float*)d_in[2];
    const float* o4  = (const float*)d_in[3];
    const float* mim = (const float*)d_in[4];
    const int*   tgt = (const int*)d_in[5];

    float* out = (float*)d_out;
    float* wavemax = (float*)d_ws;                   // NROWS floats (64 KB)

    fused_margin_softmax<<<NROWS / 4, 256, 0, stream>>>(o1, o2, o3, o4, mim, tgt,
                                                        out, wavemax);
    final_max_kernel<<<1, 1024, 0, stream>>>(wavemax, out);
}